// Round 1
// baseline (253.884 us; speedup 1.0000x reference)
//
#include <hip/hip_runtime.h>

#define NSAMP 32768
#define INF 512
#define OUTF 512
#define NB 8            // spline bases per input
#define KSP 4096        // INF * NB (spline columns)
#define KTOT 4608       // KSP + INF (silu columns)

typedef __attribute__((ext_vector_type(8))) short bf16x8;
typedef __attribute__((ext_vector_type(4))) float f32x4;

typedef __attribute__((address_space(1))) void gas_void;
typedef __attribute__((address_space(3))) void las_void;
#define GLL16(g, l) __builtin_amdgcn_global_load_lds( \
    (const gas_void*)(g), (las_void*)(l), 16, 0, 0)

// float -> bf16 round-nearest-even (W prep only)
__device__ __forceinline__ unsigned short f2bf(float f) {
  unsigned int u = __float_as_uint(f);
  u += 0x7fffu + ((u >> 16) & 1u);
  return (unsigned short)(u >> 16);
}

// pack two floats as bf16 pair (round-nearest-up). lo in low 16 bits.
__device__ __forceinline__ unsigned pack_rn(float lo, float hi) {
  return __builtin_amdgcn_perm(__float_as_uint(hi) + 0x8000u,
                               __float_as_uint(lo) + 0x8000u, 0x07060302u);
}

// 8-slot cubic B-spline basis vector, scaled by 6 (the 1/6 is folded into W).
// Branchless; out-of-grid x -> all-zero (matches reference clipping).
__device__ __forceinline__ uint4 kan_basis_vec(float xv) {
  float t = __builtin_fmaf(xv, 1.0f / 1.2f, 5.5f);   // (x+6.6)/1.2
  float cf = floorf(t);
  float u = t - cf;
  int j0 = (int)cf - 3;
  float omu = 1.0f - u;
  float u2 = u * u, u3 = u2 * u;
  float omu2 = omu * omu;
  float w0 = omu2 * omu;                                         // 6*(1/6)omu^3
  float w1 = __builtin_fmaf(3.f, u3, __builtin_fmaf(-6.f, u2, 4.f));
  float w2 = __builtin_fmaf(-3.f, u3,
              __builtin_fmaf(3.f, u2, __builtin_fmaf(3.f, u, 1.f)));
  float w3 = u3;
  unsigned P0 = pack_rn(w0, w1);
  unsigned P1 = pack_rn(w2, w3);
  // 128-bit result = [P1:P0] << (16*j0), bits outside [0,128) dropped.
  int p = j0 & 1;
  unsigned Q0 = p ? (P0 << 16) : P0;
  unsigned Q1 = p ? __builtin_amdgcn_alignbit(P1, P0, 16) : P1;
  unsigned Q2 = p ? (P1 >> 16) : 0u;
  int D = j0 >> 1;
  uint4 r;
  r.x = (D == 0) ? Q0 : (D == -1) ? Q1 : (D == -2) ? Q2 : 0u;
  r.y = (D == 1) ? Q0 : (D ==  0) ? Q1 : (D == -1) ? Q2 : 0u;
  r.z = (D == 2) ? Q0 : (D ==  1) ? Q1 : (D ==  0) ? Q2 : 0u;
  r.w = (D == 3) ? Q0 : (D ==  2) ? Q1 : (D ==  1) ? Q2 : 0u;
  return r;
}

// W_aug[o][KTOT]: cols i*8+k = spline_weight[o,i,k]*scaler[o,i]/6 (basis is 6w);
// col 4096+i = base_weight[o,i]
__global__ __launch_bounds__(256) void kan_prep_w(
    const float* __restrict__ bw, const float* __restrict__ sw,
    const float* __restrict__ sc, unsigned short* __restrict__ W) {
  int idx = blockIdx.x * 256 + threadIdx.x;   // o*512 + i
  float scv = sc[idx] * (1.0f / 6.0f);
  float4 s0 = ((const float4*)sw)[idx * 2 + 0];
  float4 s1 = ((const float4*)sw)[idx * 2 + 1];
  unsigned short v[8];
  v[0] = f2bf(s0.x * scv); v[1] = f2bf(s0.y * scv);
  v[2] = f2bf(s0.z * scv); v[3] = f2bf(s0.w * scv);
  v[4] = f2bf(s1.x * scv); v[5] = f2bf(s1.y * scv);
  v[6] = f2bf(s1.z * scv); v[7] = f2bf(s1.w * scv);
  int o = idx >> 9, i = idx & 511;
  *(bf16x8*)(W + (size_t)o * KTOT + i * NB) = *(bf16x8*)v;
  W[(size_t)o * KTOT + KSP + i] = f2bf(bw[idx]);
}

// Fragment compute on the XOR-swizzled layout: element (row, seg s) lives at
// seg s^(row&7). 64x128 per wave: av[4] x bv[8].
__device__ __forceinline__ void mfma_chunk(
    const unsigned short* As, const unsigned short* Bs,
    f32x4 acc[4][8], int wm, int wn, int frow, int quad) {
  const int fr7 = frow & 7;
  #pragma unroll
  for (int ks = 0; ks < 2; ++ks) {
    bf16x8 av[4], bv[8];
    const int sa = ((ks * 4 + quad) ^ fr7) * 8;
    #pragma unroll
    for (int f = 0; f < 4; ++f)
      av[f] = *(const bf16x8*)&As[(wm + f * 16 + frow) * 64 + sa];
    #pragma unroll
    for (int g = 0; g < 8; ++g)
      bv[g] = *(const bf16x8*)&Bs[(wn + g * 16 + frow) * 64 + sa];
    #pragma unroll
    for (int mf = 0; mf < 4; ++mf)
      #pragma unroll
      for (int nf = 0; nf < 8; ++nf)
        acc[mf][nf] = __builtin_amdgcn_mfma_f32_16x16x32_bf16(
            av[mf], bv[nf], acc[mf][nf], 0, 0, 0);
  }
}

// Fused out = A_aug(x) @ W_aug^T. 128(M) x 256(N) tile per 256-thread block.
// Phase 1 is software-pipelined (T3/T4/T5): B-loads for chunk kc+1 issued
// before the MFMA on chunk kc, raw s_barriers with counted vmcnt (never a
// vmcnt(0) drain before the pre-MFMA barrier), setprio(1) around the MFMA
// cluster. As stays single-buffered: its writes happen only after the
// post-MFMA barrier, so no extra LDS and no race.
__global__ __launch_bounds__(256, 2) void kan_fused(
    const float* __restrict__ x, const unsigned short* __restrict__ W,
    float* __restrict__ out) {
  __shared__ __align__(16) unsigned short As[128 * 64];        // 16 KB
  __shared__ __align__(16) unsigned short Bs[2][256 * 64];     // 64 KB ping-pong
  const int tid = threadIdx.x;
  const int wave = tid >> 6;
  const int lane = tid & 63;
  const int frow = lane & 15;
  const int quad = lane >> 4;
  const int lr = lane >> 3;     // row within 8-row group
  const int lc = lane & 7;      // 16B-segment / input within group
  // ntile-siblings 256 apart -> same XCD (round-robin %8) -> x shared in L2
  const int mtile = blockIdx.x & 255;
  const int ntile = blockIdx.x >> 8;          // 0..1
  const int wm = (wave & 1) << 6;
  const int wn = (wave >> 1) << 7;            // 0 or 128

  f32x4 acc[4][8];
  #pragma unroll
  for (int i = 0; i < 4; ++i)
    #pragma unroll
    for (int j = 0; j < 8; ++j)
      acc[i][j] = (f32x4){0.f, 0.f, 0.f, 0.f};

  // B staging: wave covers 64 rows (8 groups of 8). Source seg XORed by lr so
  // the lane-linear GLL16 deposit lands swizzled. +64 cols/chunk; after 64
  // chunks pointers sit exactly at the silu columns (KSP).
  const unsigned short* bgp[8];
  #pragma unroll
  for (int is = 0; is < 8; ++is)
    bgp[is] = W + (size_t)(ntile * 256 + wave * 64 + is * 8 + lr) * KTOT +
              ((lc ^ lr) * 8);
  const float* xb = x + (size_t)mtile * 128 * INF;
  const float* xp[4];
  #pragma unroll
  for (int is = 0; is < 4; ++is)
    xp[is] = xb + (size_t)(wave * 32 + is * 8 + lr) * INF + lc;

  // ---- Prologue: basis(0) -> As, B(0) -> Bs[0] ----
  {
    #pragma unroll
    for (int is = 0; is < 4; ++is) {
      const int row = wave * 32 + is * 8 + lr;
      uint4 bb = kan_basis_vec(xp[is][0]);
      *(uint4*)&As[row * 64 + ((lc ^ lr) * 8)] = bb;
    }
    #pragma unroll
    for (int is = 0; is < 8; ++is) {
      GLL16(bgp[is], &Bs[0][(wave * 64 + is * 8) * 64]);
      bgp[is] += 64;
    }
  }

  // ---- Phase 1: 64 spline chunks, pipelined ----
  // per iter: [a] issue B(kc+1) + x(kc+1) loads  (12 vmem ops)
  //           [b] vmcnt(12) — retires chunk-kc loads only, keeps the 12
  //               current-iter loads in flight across the barrier + MFMA
  //           [c] setprio(1) MFMA(kc) setprio(0)
  //           [d] barrier — all As readers done
  //           [e] basis(kc+1) -> As   (B(kc+1) latency hides under b..e)
  for (int kc = 0; kc < 64; ++kc) {
    if (kc < 63) {
      #pragma unroll
      for (int is = 0; is < 8; ++is) {
        GLL16(bgp[is], &Bs[(kc + 1) & 1][(wave * 64 + is * 8) * 64]);
        bgp[is] += 64;
      }
    }
    float xn[4];
    const int knext = ((kc + 1) & 63) * 8;
    #pragma unroll
    for (int is = 0; is < 4; ++is) xn[is] = xp[is][knext];

    asm volatile("s_waitcnt vmcnt(12) lgkmcnt(0)" ::: "memory");
    asm volatile("s_barrier" ::: "memory");
    __builtin_amdgcn_s_setprio(1);
    mfma_chunk(As, Bs[kc & 1], acc, wm, wn, frow, quad);
    __builtin_amdgcn_s_setprio(0);
    asm volatile("s_barrier" ::: "memory");

    if (kc < 63) {
      #pragma unroll
      for (int is = 0; is < 4; ++is) {
        const int row = wave * 32 + is * 8 + lr;
        uint4 bb = kan_basis_vec(xn[is]);
        *(uint4*)&As[row * 64 + ((lc ^ lr) * 8)] = bb;
      }
    }
  }

  // ---- Phase 2: silu columns, 8 chunks of 64 inputs (11% of K) ----
  // Simple drain-style loop on Bs[0] (keeps register pressure flat; the
  // pipeline win here would be ~1-2 us at +32 VGPR live across MFMA).
  for (int sc = 0; sc < 8; ++sc) {
    float4 v0[4], v1[4];
    #pragma unroll
    for (int is = 0; is < 4; ++is) {
      const int row = wave * 32 + is * 8 + lr;
      const float* xr = xb + (size_t)row * INF + sc * 64 + lc * 8;
      v0[is] = *(const float4*)xr;
      v1[is] = *(const float4*)(xr + 4);
    }
    #pragma unroll
    for (int is = 0; is < 8; ++is) {
      GLL16(bgp[is], &Bs[0][(wave * 64 + is * 8) * 64]);
      bgp[is] += 64;
    }
    #pragma unroll
    for (int is = 0; is < 4; ++is) {
      const int row = wave * 32 + is * 8 + lr;
      float vv[8] = {v0[is].x, v0[is].y, v0[is].z, v0[is].w,
                     v1[is].x, v1[is].y, v1[is].z, v1[is].w};
      float s[8];
      #pragma unroll
      for (int e = 0; e < 8; ++e)
        s[e] = vv[e] * __builtin_amdgcn_rcpf(1.0f + __expf(-vv[e]));
      uint4 pk;
      pk.x = pack_rn(s[0], s[1]);
      pk.y = pack_rn(s[2], s[3]);
      pk.z = pack_rn(s[4], s[5]);
      pk.w = pack_rn(s[6], s[7]);
      *(uint4*)&As[row * 64 + ((lc ^ lr) * 8)] = pk;
    }
    __syncthreads();
    __builtin_amdgcn_s_setprio(1);
    mfma_chunk(As, Bs[0], acc, wm, wn, frow, quad);
    __builtin_amdgcn_s_setprio(0);
    __syncthreads();
  }

  // ---- Epilogue ----
  const size_t m0 = (size_t)mtile * 128;
  const int n0 = ntile * 256;
  #pragma unroll
  for (int mf = 0; mf < 4; ++mf)
    #pragma unroll
    for (int nf = 0; nf < 8; ++nf)
      #pragma unroll
      for (int r = 0; r < 4; ++r)
        out[(m0 + wm + mf * 16 + quad * 4 + r) * OUTF + (n0 + wn + nf * 16 + frow)] =
            acc[mf][nf][r];
}

// Correct-but-slow fp32 fallback (only if ws can't hold W_aug: 4.7 MB)
__global__ __launch_bounds__(256) void kan_naive(
    const float* __restrict__ x, const float* __restrict__ bw,
    const float* __restrict__ sw, const float* __restrict__ sc,
    float* __restrict__ out) {
  int idx = blockIdx.x * 256 + threadIdx.x;
  int n = idx >> 9, o = idx & 511;
  const float* xr = x + (size_t)n * INF;
  float acc = 0.f;
  for (int i = 0; i < INF; ++i) {
    float xv = xr[i];
    float sil = xv / (1.0f + __expf(-xv));
    float t = (xv + 6.6f) * (1.0f / 1.2f);
    float cf = floorf(t);
    float u = t - cf;
    int j0 = (int)cf - 3;
    float omu = 1.0f - u;
    float u2 = u * u, u3 = u2 * u;
    float w[4];
    w[0] = (1.0f / 6.0f) * omu * omu * omu;
    w[1] = (1.0f / 6.0f) * (3.0f * u3 - 6.0f * u2 + 4.0f);
    w[2] = (1.0f / 6.0f) * (-3.0f * u3 + 3.0f * u2 + 3.0f * u + 1.0f);
    w[3] = (1.0f / 6.0f) * u3;
    int wi = o * INF + i;
    acc += sil * bw[wi];
    float sp = 0.f;
    #pragma unroll
    for (int m = 0; m < 4; ++m) {
      int j = j0 + m;
      if ((unsigned)j < 8u) sp += w[m] * sw[wi * NB + j];
    }
    acc += sp * sc[wi];
  }
  out[idx] = acc;
}

extern "C" void kernel_launch(void* const* d_in, const int* in_sizes, int n_in,
                              void* d_out, int out_size, void* d_ws, size_t ws_size,
                              hipStream_t stream) {
  const float* x  = (const float*)d_in[0];
  const float* bw = (const float*)d_in[1];
  const float* sw = (const float*)d_in[2];
  const float* sc = (const float*)d_in[3];
  float* out = (float*)d_out;

  const size_t wbytes = (size_t)OUTF * KTOT * 2;    // 4.72 MB
  if (ws_size >= wbytes) {
    unsigned short* W = (unsigned short*)d_ws;
    kan_prep_w<<<(OUTF * INF) / 256, 256, 0, stream>>>(bw, sw, sc, W);
    kan_fused<<<(NSAMP / 128) * (OUTF / 256), 256, 0, stream>>>(x, W, out);
  } else {
    kan_naive<<<(NSAMP * OUTF) / 256, 256, 0, stream>>>(x, bw, sw, sc, out);
  }
}